// Round 2
// baseline (46659.872 us; speedup 1.0000x reference)
//
#include <hip/hip_runtime.h>

#define BB 8
#define CC 96
#define TT 1000
#define FF 64
#define LL 12
// gates: 3*CC = 288 output rows per projection

__device__ __forceinline__ float sigmoidf_(float v) {
    return 1.0f / (1.0f + __expf(-v));
}

// One block = one (cell, b, f-half): 32 columns (b fixed, 32 f values), all 288 rows.
// Column-only split keeps both RMSNorm reductions block-local.
union SmemU {
    float hp[CC][35];        // hp with halo (34 cols, pad 35) -- used in phases A/B
    float w[2][288][12];     // weight K-chunk stage (xw, pw), 8 cols pad 12 -- used in matmul
};

__global__ __launch_bounds__(256) void cell_diag(
    const float* __restrict__ x,
    const float* __restrict__ inw_all,
    const float* __restrict__ hnw_all,
    const float* __restrict__ xw_all,
    const float* __restrict__ xb_all,
    const float* __restrict__ hw_all,
    const float* __restrict__ hb_all,
    const float* __restrict__ pw_all,
    const float* __restrict__ pb_all,
    const float* __restrict__ onw_all,
    float* __restrict__ out,
    float* __restrict__ H,     // [2][LL][BB][CC][FF] ping-pong state; slot l holds
                               // layer l's most recent output (== its state)
    int d, int l_start)
{
    const int cell = blockIdx.x >> 4;
    const int sub  = blockIdx.x & 15;
    const int l = l_start + cell;
    const int t = d - l;
    const int b = sub >> 1;
    const int f0 = (sub & 1) << 5;   // 0 or 32

    __shared__ __align__(16) float ybuf[CC][36];  // raw y (also reused for h_new + y)
    __shared__ __align__(16) float hnb[CC][36];   // dwconv(rms(hp)) output = hg matmul input
    __shared__ __align__(16) SmemU su;
    __shared__ float s_y[32];
    __shared__ float s_h[34];

    const int tid = threadIdx.x;

    const float* inw = inw_all + l*CC;
    const float* hnw = hnw_all + l*CC;
    const float* xw  = xw_all + (size_t)l*288*CC;
    const float* xb  = xb_all + l*288;
    const float* hw  = hw_all + l*CC*3;
    const float* hb  = hb_all + l*CC;
    const float* pw  = pw_all + (size_t)l*288*CC;
    const float* pb  = pb_all + l*288;
    const float* onw = onw_all + l*CC;

    // Both y (layer l-1 @ t) and hp (layer l @ t-1) were produced on diag d-1.
    const int bufW = d & 1;
    const int bufR = (d + 1) & 1;

    // ---- Phase A: stage raw y and hp(+halo) into LDS ----
    const float* ysrc;
    int ystride;
    if (l == 0) { ysrc = x + (size_t)b*CC*TT*FF + (size_t)t*FF + f0; ystride = TT*FF; }
    else        { ysrc = H + ((((size_t)bufR*LL + (l-1))*BB + b)*CC)*FF + f0; ystride = FF; }

    #pragma unroll
    for (int i = 0; i < 12; i++) {
        int idx = i*256 + tid;
        int c = idx >> 5, j = idx & 31;
        ybuf[c][j] = ysrc[(size_t)c*ystride + j];
    }

    const float* hpsrc = H + ((((size_t)bufR*LL + l)*BB + b)*CC)*FF;
    for (int idx = tid; idx < CC*34; idx += 256) {
        int c = idx / 34, jh = idx % 34;
        int f = f0 - 1 + jh;         // global f of halo column jh
        float v = 0.0f;
        if (t > 0 && f >= 0 && f < FF) v = hpsrc[c*FF + f];
        su.hp[c][jh] = v;
    }
    __syncthreads();

    // ---- per-column RMS stats (over C) ----
    if (tid < 32) {
        float s = 0.0f;
        for (int c = 0; c < CC; c++) { float v = ybuf[c][tid]; s += v*v; }
        s_y[tid] = rsqrtf(s * (1.0f/CC) + 1e-6f);
    } else if (tid >= 64 && tid < 98) {
        int jh = tid - 64;
        float s = 0.0f;
        for (int c = 0; c < CC; c++) { float v = su.hp[c][jh]; s += v*v; }
        s_h[jh] = rsqrtf(s * (1.0f/CC) + 1e-6f);
    }
    __syncthreads();

    // ---- Phase B: depthwise conv (K=3) on rms(hp)*hnw, +hb -> hnb ----
    #pragma unroll
    for (int i = 0; i < 12; i++) {
        int idx = i*256 + tid;
        int c = idx >> 5, j = idx & 31;
        float w0 = hw[c*3+0], w1 = hw[c*3+1], w2 = hw[c*3+2];
        float p0 = su.hp[c][j]   * s_h[j];
        float p1 = su.hp[c][j+1] * s_h[j+1];
        float p2 = su.hp[c][j+2] * s_h[j+2];
        hnb[c][j] = (w0*p0 + w1*p1 + w2*p2) * hnw[c] + hb[c];
    }
    __syncthreads();   // also fences su.hp reads before su.w overwrites it

    // ---- Matmuls: xg = xw @ (y*s_y*inw), hg = pw @ hnb; both fused ----
    // thread: tx in 0..7 -> 4 columns, ty in 0..31 -> co = ty+32a (a=0..2), gates g=0..2
    const int tx = tid & 7, ty = tid >> 3;
    const int j0 = tx << 2;
    float accx[3][3][4];
    float accp[3][3][4];
    #pragma unroll
    for (int a = 0; a < 3; a++)
        #pragma unroll
        for (int g = 0; g < 3; g++)
            #pragma unroll
            for (int m = 0; m < 4; m++) { accx[a][g][m] = 0.0f; accp[a][g][m] = 0.0f; }

    float syj[4];
    #pragma unroll
    for (int m = 0; m < 4; m++) syj[m] = s_y[j0 + m];

    for (int cc8 = 0; cc8 < 12; cc8++) {
        int c0 = cc8 * 8;
        // stage 288x8 chunks of xw and pw (2304 elems each, 9 per thread)
        #pragma unroll
        for (int i = 0; i < 9; i++) {
            int idx = i*256 + tid;
            int o = idx >> 3, ci = idx & 7;
            su.w[0][o][ci] = xw[(size_t)o*CC + c0 + ci];
            su.w[1][o][ci] = pw[(size_t)o*CC + c0 + ci];
        }
        __syncthreads();
        #pragma unroll
        for (int c4 = 0; c4 < 2; c4++) {
            int cl = c4 * 4;
            int cg = c0 + cl;
            float ya[4][4], ha[4][4];
            #pragma unroll
            for (int k = 0; k < 4; k++) {
                const float4 yv = *(const float4*)&ybuf[cg + k][j0];
                const float4 hv = *(const float4*)&hnb[cg + k][j0];
                float sc = inw[cg + k];
                ya[k][0] = yv.x * syj[0] * sc;
                ya[k][1] = yv.y * syj[1] * sc;
                ya[k][2] = yv.z * syj[2] * sc;
                ya[k][3] = yv.w * syj[3] * sc;
                ha[k][0] = hv.x; ha[k][1] = hv.y; ha[k][2] = hv.z; ha[k][3] = hv.w;
            }
            #pragma unroll
            for (int a = 0; a < 3; a++)
                #pragma unroll
                for (int g = 0; g < 3; g++) {
                    int row = ty + 32*a + 96*g;
                    const float4 wx4 = *(const float4*)&su.w[0][row][cl];
                    const float4 wp4 = *(const float4*)&su.w[1][row][cl];
                    #pragma unroll
                    for (int m = 0; m < 4; m++) {
                        accx[a][g][m] += wx4.x*ya[0][m] + wx4.y*ya[1][m]
                                       + wx4.z*ya[2][m] + wx4.w*ya[3][m];
                        accp[a][g][m] += wp4.x*ha[0][m] + wp4.y*ha[1][m]
                                       + wp4.z*ha[2][m] + wp4.w*ha[3][m];
                    }
                }
        }
        __syncthreads();
    }

    // ---- GRU epilogue (in-register), write h_new + y back into ybuf ----
    #pragma unroll
    for (int a = 0; a < 3; a++) {
        int co = ty + 32*a;
        float xbr = xb[co], xbz = xb[co+96], xbn = xb[co+192];
        float pbr = pb[co], pbz = pb[co+96], pbn = pb[co+192];
        #pragma unroll
        for (int m = 0; m < 4; m++) {
            int j = j0 + m;
            float r = sigmoidf_(accx[a][0][m] + xbr + accp[a][0][m] + pbr);
            float z = sigmoidf_(accx[a][1][m] + xbz + accp[a][1][m] + pbz);
            float cn = tanhf(accx[a][2][m] + xbn + r * (accp[a][2][m] + pbn));
            float hpv = (t > 0) ? hpsrc[co*FF + f0 + j] : 0.0f;   // raw hp (L2-warm)
            float hnew = (1.0f - z) * cn + z * hpv;
            ybuf[co][j] = hnew + ybuf[co][j];
        }
    }
    __syncthreads();

    // ---- out_norm stats ----
    if (tid < 32) {
        float s = 0.0f;
        for (int c = 0; c < CC; c++) { float v = ybuf[c][tid]; s += v*v; }
        s_y[tid] = rsqrtf(s * (1.0f/CC) + 1e-6f);
    }
    __syncthreads();

    // ---- write state (and final output for last layer) ----
    float* hdst = H + ((((size_t)bufW*LL + l)*BB + b)*CC)*FF + f0;
    float* odst = out + (size_t)b*CC*TT*FF + (size_t)t*FF + f0;
    #pragma unroll
    for (int i = 0; i < 12; i++) {
        int idx = i*256 + tid;
        int c = idx >> 5, j = idx & 31;
        float v = ybuf[c][j] * s_y[j] * onw[c];
        hdst[(size_t)c*FF + j] = v;
        if (l == LL-1) odst[(size_t)c*TT*FF + j] = v;
    }
}

extern "C" void kernel_launch(void* const* d_in, const int* in_sizes, int n_in,
                              void* d_out, int out_size, void* d_ws, size_t ws_size,
                              hipStream_t stream) {
    const float* x   = (const float*)d_in[0];
    const float* inw = (const float*)d_in[1];
    const float* hnw = (const float*)d_in[2];
    const float* xw  = (const float*)d_in[3];
    const float* xb  = (const float*)d_in[4];
    const float* hw  = (const float*)d_in[5];
    const float* hb  = (const float*)d_in[6];
    const float* pw  = (const float*)d_in[7];
    const float* pb  = (const float*)d_in[8];
    const float* onw = (const float*)d_in[9];
    float* out = (float*)d_out;
    float* H   = (float*)d_ws;   // needs 2*LL*BB*CC*FF*4 = 4.72 MB

    // wavefront over anti-diagonals d = l + t
    for (int d = 0; d < TT + LL - 1; d++) {
        int l_lo = d - (TT - 1); if (l_lo < 0) l_lo = 0;
        int l_hi = d;            if (l_hi > LL - 1) l_hi = LL - 1;
        int nact = l_hi - l_lo + 1;
        cell_diag<<<dim3(nact * 16), dim3(256), 0, stream>>>(
            x, inw, hnw, xw, xb, hw, hb, pw, pb, onw, out, H, d, l_lo);
    }
}